// Round 10
// baseline (268.032 us; speedup 1.0000x reference)
//
#include <hip/hip_runtime.h>
#include <hip/hip_bf16.h>
#include <stdint.h>

#define SEQ_LEN 3120
#define DIM 1536
#define QKV_N 4608
#define HEADS 12
#define HEAD_DIM 128
#define FRAME_LEN 1560
#define SM_SCALE 0.08838834764831845f   // 1/sqrt(128)
#define LOG2E 1.4426950408889634f
#define FMAXC2 43.280851226669165f      // 30*log2e; p = 2^(s' - 43.28), s' = s*log2e
#define BQ 256                           // q rows per attention block (8 waves x 32)

#if __has_builtin(__builtin_amdgcn_exp2f)
#define FEXP2(x) __builtin_amdgcn_exp2f(x)
#else
#define FEXP2(x) exp2f(x)
#endif

typedef short short8 __attribute__((ext_vector_type(8)));
typedef float f32x4 __attribute__((ext_vector_type(4)));
typedef float f32x16 __attribute__((ext_vector_type(16)));

__device__ __forceinline__ unsigned short f2bf(float x) {
    union { float f; unsigned u; } v; v.f = x;
    unsigned r = v.u + 0x7fffu + ((v.u >> 16) & 1u);
    return (unsigned short)(r >> 16);
}
__device__ __forceinline__ float bf2f(unsigned short b) {
    union { unsigned u; float f; } v; v.u = ((unsigned)b) << 16;
    return v.f;
}
__device__ __forceinline__ unsigned pk2bf(float a, float b) {
    __hip_bfloat162 h = __float22bfloat162_rn(make_float2(a, b));
    union { __hip_bfloat162 h2; unsigned u; } v; v.h2 = h;
    return v.u;
}

__device__ __forceinline__ void async16(void* lds, const void* g) {
    __builtin_amdgcn_global_load_lds(
        (const __attribute__((address_space(1))) unsigned int*)g,
        (__attribute__((address_space(3))) unsigned int*)lds, 16, 0, 0);
}

// ---------------------------------------------------------------------------
// Fused prep: hs->bf16 convert (blocks 0..2339), w_qkv transpose (2340..4067),
// w_out transpose (4068..4643). One launch instead of three.
// ---------------------------------------------------------------------------
__device__ __forceinline__ void transpose_tile(
    const float* __restrict__ in, unsigned short* __restrict__ out,
    int R, int C, int c0, int r0, float (*T)[65], int tid)
{
    const int rl = tid >> 4, cl = (tid & 15) * 4;
#pragma unroll
    for (int i = 0; i < 4; ++i) {
        const int row = r0 + rl + i * 16;
        float4 v = *(const float4*)&in[(size_t)row * C + c0 + cl];
        T[cl + 0][rl + i * 16] = v.x; T[cl + 1][rl + i * 16] = v.y;
        T[cl + 2][rl + i * 16] = v.z; T[cl + 3][rl + i * 16] = v.w;
    }
    __syncthreads();
    const int oc = tid >> 2, ob = (tid & 3) * 16;
    union { unsigned short t[16]; uint4 u[2]; } p;
#pragma unroll
    for (int j = 0; j < 16; ++j) p.t[j] = f2bf(T[oc][ob + j]);
    uint4* dst = (uint4*)&out[(size_t)(c0 + oc) * R + r0 + ob];
    dst[0] = p.u[0];
    dst[1] = p.u[1];
}

__global__ __launch_bounds__(256) void prep_kernel(
    const float* __restrict__ hs, unsigned short* __restrict__ hsb,
    const float* __restrict__ w_qkv, unsigned short* __restrict__ wqkvT,
    const float* __restrict__ w_out, unsigned short* __restrict__ woutT)
{
    __shared__ float T[64][65];
    const int bid = blockIdx.x;
    const int tid = threadIdx.x;
    if (bid < 2340) {
        const int i = bid * 256 + tid;
        const float4 a = ((const float4*)hs)[i * 2];
        const float4 b = ((const float4*)hs)[i * 2 + 1];
        union { unsigned short t[8]; uint4 u; } p;
        p.t[0] = f2bf(a.x); p.t[1] = f2bf(a.y); p.t[2] = f2bf(a.z); p.t[3] = f2bf(a.w);
        p.t[4] = f2bf(b.x); p.t[5] = f2bf(b.y); p.t[6] = f2bf(b.z); p.t[7] = f2bf(b.w);
        ((uint4*)hsb)[i] = p.u;
    } else if (bid < 4068) {
        const int t = bid - 2340; // 72 x 24 tiles of w_qkv [1536][4608]
        transpose_tile(w_qkv, wqkvT, DIM, QKV_N, (t % 72) * 64, (t / 72) * 64, T, tid);
    } else {
        const int t = bid - 4068; // 24 x 24 tiles of w_out [1536][1536]
        transpose_tile(w_out, woutT, DIM, DIM, (t % 24) * 64, (t / 24) * 64, T, tid);
    }
}

// ---------------------------------------------------------------------------
// 128^2-tile fp32-out GEMM (output projection), gemm256 schedule ported:
// BK=64, 4 waves (2Mx2N), 64KB LDS double-buffer, both-sides XOR swizzle,
// issue-early staging, single raw vmcnt(0)+s_barrier per K-tile, setprio.
// Grid: bijective n-major chunked XCD mapping over 25x12=300 tiles.
// ---------------------------------------------------------------------------
__global__ __launch_bounds__(256, 2) void gemm128_f32_kernel(
    const unsigned short* __restrict__ A, const unsigned short* __restrict__ Bt,
    const float* __restrict__ bias, float* __restrict__ C, int M, int N, int K)
{
    __shared__ short LDS[32768]; // [A0 8192 | B0 8192 | A1 8192 | B1 8192]

    const int mtiles = (M + 127) >> 7;
    const int nwg = mtiles * (N >> 7);
    const int q = nwg >> 3, r = nwg & 7;
    const int xcd = blockIdx.x & 7;
    const int cnt = q + (xcd < r ? 1 : 0);
    const int li = blockIdx.x >> 3;
    if (li >= cnt) return;
    const int g0 = (xcd < r) ? xcd * (q + 1) : r * (q + 1) + (xcd - r) * q;
    const int g = g0 + li;
    const int m0 = (g % mtiles) * 128;
    const int n0 = (g / mtiles) * 128;

    const int tid = threadIdx.x;
    const int w = tid >> 6, l = tid & 63;
    const int wr = w >> 1, wc = w & 1;         // 2 x 2 wave grid
    const int lhi = l >> 4, llo = l & 15;

    f32x4 acc[4][4];
#pragma unroll
    for (int i = 0; i < 4; ++i)
#pragma unroll
        for (int j = 0; j < 4; ++j) acc[i][j] = f32x4{0.f, 0.f, 0.f, 0.f};

    const unsigned short* gsrc[8];
#pragma unroll
    for (int j = 0; j < 4; ++j) {
        const int c = (j * 4 + w) * 64 + l;
        const int row = c >> 3, ks = c & 7;
        gsrc[j] = A + (size_t)min(m0 + row, M - 1) * K + (ks ^ (row & 7)) * 8;
    }
#pragma unroll
    for (int j = 0; j < 4; ++j) {
        const int c = (j * 4 + w) * 64 + l;
        const int row = c >> 3, ks = c & 7;
        gsrc[4 + j] = Bt + (size_t)min(n0 + row, N - 1) * K + (ks ^ (row & 7)) * 8;
    }

    auto stageAll = [&](int kt, int b) {
        short* dst = LDS + b * 16384;
#pragma unroll
        for (int j = 0; j < 4; ++j)
            async16(dst + (j * 4 + w) * 512, gsrc[j] + kt * 64);
#pragma unroll
        for (int j = 0; j < 4; ++j)
            async16(dst + 8192 + (j * 4 + w) * 512, gsrc[4 + j] + kt * 64);
    };

    const int nk = K >> 6;
    stageAll(0, 0);
    asm volatile("s_waitcnt vmcnt(0)\n\ts_barrier" ::: "memory");

    for (int t = 0; t < nk; ++t) {
        if (t + 1 < nk) stageAll(t + 1, (t + 1) & 1);   // issue early
        const short* Ab = LDS + (t & 1) * 16384;
        const short* Bb = Ab + 8192;
#pragma unroll
        for (int ph = 0; ph < 2; ++ph) {                // k-step = ph*32
            short8 bfr[4], afr[4];
#pragma unroll
            for (int nt = 0; nt < 4; ++nt) {
                const int rb = wc * 64 + nt * 16 + llo;
                bfr[nt] = *(const short8*)&Bb[rb * 64 + ((ph * 4 + lhi) ^ (rb & 7)) * 8];
            }
#pragma unroll
            for (int mt = 0; mt < 4; ++mt) {
                const int ra = wr * 64 + mt * 16 + llo;
                afr[mt] = *(const short8*)&Ab[ra * 64 + ((ph * 4 + lhi) ^ (ra & 7)) * 8];
            }
            __builtin_amdgcn_s_setprio(1);
#pragma unroll
            for (int mt = 0; mt < 4; ++mt)
#pragma unroll
                for (int nt = 0; nt < 4; ++nt)
                    acc[mt][nt] = __builtin_amdgcn_mfma_f32_16x16x32_bf16(
                        afr[mt], bfr[nt], acc[mt][nt], 0, 0, 0);
            __builtin_amdgcn_s_setprio(0);
        }
        asm volatile("s_waitcnt vmcnt(0)\n\ts_barrier" ::: "memory");
    }

#pragma unroll
    for (int mt = 0; mt < 4; ++mt)
#pragma unroll
        for (int ri = 0; ri < 4; ++ri) {
            const int row = m0 + wr * 64 + mt * 16 + lhi * 4 + ri;
            if (row < M) {
#pragma unroll
                for (int nt = 0; nt < 4; ++nt) {
                    const int col = n0 + wc * 64 + nt * 16 + llo;
                    C[(size_t)row * N + col] = acc[mt][nt][ri] + bias[col];
                }
            }
        }
}

// ---------------------------------------------------------------------------
// 256^2-tile bf16 GEMM (qkv projection). BK=64, 8 waves (2Mx4N), 128KB LDS
// double-buffer, T2 swizzle (both-sides), issue-early/drain-late, raw
// vmcnt(0)+s_barrier once per K-tile, s_setprio around MFMA clusters.
// ---------------------------------------------------------------------------
__global__ __launch_bounds__(512, 2) void gemm256_bf16_kernel(
    const unsigned short* __restrict__ A, const unsigned short* __restrict__ Bt,
    const float* __restrict__ bias, unsigned short* __restrict__ C,
    int M, int N, int K)
{
    __shared__ short LDS[65536]; // [A0 | B0 | A1 | B1] x 16384 shorts

    const int mtiles = (M + 255) >> 8;
    const int nwg = mtiles * (N >> 8);
    const int q = nwg >> 3, r = nwg & 7;
    const int xcd = blockIdx.x & 7;
    const int g0 = (xcd < r) ? xcd * (q + 1) : r * (q + 1) + (xcd - r) * q;
    const int g = g0 + (int)(blockIdx.x >> 3);
    const int m0 = (g % mtiles) * 256;
    const int n0 = (g / mtiles) * 256;

    const int tid = threadIdx.x;
    const int w = tid >> 6, l = tid & 63;
    const int wr = w >> 2, wc = w & 3;          // 2 x 4 wave grid
    const int lhi = l >> 4, llo = l & 15;

    f32x4 acc[8][4];
#pragma unroll
    for (int i = 0; i < 8; ++i)
#pragma unroll
        for (int j = 0; j < 4; ++j) acc[i][j] = f32x4{0.f, 0.f, 0.f, 0.f};

    const unsigned short* gsrc[8];
#pragma unroll
    for (int j = 0; j < 4; ++j) {
        const int c = (j * 8 + w) * 64 + l;
        const int row = c >> 3, ks = c & 7;
        gsrc[j] = A + (size_t)min(m0 + row, M - 1) * K + (ks ^ (row & 7)) * 8;
    }
#pragma unroll
    for (int j = 0; j < 4; ++j) {
        const int c = (j * 8 + w) * 64 + l;
        const int row = c >> 3, ks = c & 7;
        gsrc[4 + j] = Bt + (size_t)min(n0 + row, N - 1) * K + (ks ^ (row & 7)) * 8;
    }

    auto stageAll = [&](int kt, int b) {
        short* dst = LDS + b * 32768;
#pragma unroll
        for (int j = 0; j < 4; ++j)
            async16(dst + (j * 8 + w) * 512, gsrc[j] + kt * 64);
#pragma unroll
        for (int j = 0; j < 4; ++j)
            async16(dst + 16384 + (j * 8 + w) * 512, gsrc[4 + j] + kt * 64);
    };

    const int nk = K >> 6;
    stageAll(0, 0);
    asm volatile("s_waitcnt vmcnt(0)\n\ts_barrier" ::: "memory");

    for (int t = 0; t < nk; ++t) {
        if (t + 1 < nk) stageAll(t + 1, (t + 1) & 1);   // issue early
        const short* Ab = LDS + (t & 1) * 32768;
        const short* Bb = Ab + 16384;
#pragma unroll
        for (int ph = 0; ph < 2; ++ph) {                // k-step = ph*32
            short8 bfr[4];
#pragma unroll
            for (int nt = 0; nt < 4; ++nt) {
                const int rb = wc * 64 + nt * 16 + llo;
                bfr[nt] = *(const short8*)&Bb[rb * 64 + ((ph * 4 + lhi) ^ (rb & 7)) * 8];
            }
#pragma unroll
            for (int mh = 0; mh < 2; ++mh) {
                short8 afr[4];
#pragma unroll
                for (int mt = 0; mt < 4; ++mt) {
                    const int ra = wr * 128 + mh * 64 + mt * 16 + llo;
                    afr[mt] = *(const short8*)&Ab[ra * 64 + ((ph * 4 + lhi) ^ (ra & 7)) * 8];
                }
                __builtin_amdgcn_s_setprio(1);
#pragma unroll
                for (int mt = 0; mt < 4; ++mt)
#pragma unroll
                    for (int nt = 0; nt < 4; ++nt)
                        acc[mh * 4 + mt][nt] = __builtin_amdgcn_mfma_f32_16x16x32_bf16(
                            afr[mt], bfr[nt], acc[mh * 4 + mt][nt], 0, 0, 0);
                __builtin_amdgcn_s_setprio(0);
            }
        }
        asm volatile("s_waitcnt vmcnt(0)\n\ts_barrier" ::: "memory");
    }

#pragma unroll
    for (int mi = 0; mi < 8; ++mi)
#pragma unroll
        for (int ri = 0; ri < 4; ++ri) {
            const int row = m0 + wr * 128 + mi * 16 + lhi * 4 + ri;
            if (row < M) {
#pragma unroll
                for (int nt = 0; nt < 4; ++nt) {
                    const int col = n0 + wc * 64 + nt * 16 + llo;
                    C[(size_t)row * N + col] = f2bf(acc[mi][nt][ri] + bias[col]);
                }
            }
        }
}

// ---------------------------------------------------------------------------
// Fused RMSNorm+RoPE (blocks 0..3119) and V-transpose (blocks 3120..3707).
// ---------------------------------------------------------------------------
__global__ __launch_bounds__(256) void rope_vt_kernel(
    const unsigned short* __restrict__ qkvb, const float* __restrict__ gq,
    const float* __restrict__ gk, const float* __restrict__ cosf,
    const float* __restrict__ sinf, unsigned short* __restrict__ qb,
    unsigned short* __restrict__ kb, unsigned short* __restrict__ vt)
{
    __shared__ unsigned short T[128][72];
    __shared__ float wq[4], wk[4];
    const int bid = blockIdx.x;
    const int tid = threadIdx.x;

    if (bid < SEQ_LEN) {
        const int s = bid;
        const unsigned short* qrow = qkvb + (size_t)s * QKV_N;
        const unsigned short* krow = qrow + DIM;

        float2 qp[3], kp[3];
        float ssq_q = 0.f, ssq_k = 0.f;
#pragma unroll
        for (int j = 0; j < 3; ++j) {
            const int p = tid + j * 256;
            const unsigned uq = *(const unsigned*)(qrow + 2 * p);
            const unsigned uk = *(const unsigned*)(krow + 2 * p);
            qp[j] = make_float2(bf2f((unsigned short)(uq & 0xffff)), bf2f((unsigned short)(uq >> 16)));
            kp[j] = make_float2(bf2f((unsigned short)(uk & 0xffff)), bf2f((unsigned short)(uk >> 16)));
            ssq_q += qp[j].x * qp[j].x + qp[j].y * qp[j].y;
            ssq_k += kp[j].x * kp[j].x + kp[j].y * kp[j].y;
        }
#pragma unroll
        for (int off = 32; off > 0; off >>= 1) {
            ssq_q += __shfl_down(ssq_q, off);
            ssq_k += __shfl_down(ssq_k, off);
        }
        const int wave = tid >> 6, lane = tid & 63;
        if (lane == 0) { wq[wave] = ssq_q; wk[wave] = ssq_k; }
        __syncthreads();
        const float tq = wq[0] + wq[1] + wq[2] + wq[3];
        const float tk = wk[0] + wk[1] + wk[2] + wk[3];
        const float inv_q = rsqrtf(tq * (1.0f / DIM) + 1e-6f) * (SM_SCALE * LOG2E);
        const float inv_k = rsqrtf(tk * (1.0f / DIM) + 1e-6f);

#pragma unroll
        for (int j = 0; j < 3; ++j) {
            const int p = tid + j * 256;
            const int fi = p & 63;
            const float c = cosf[s * 64 + fi];
            const float si = sinf[s * 64 + fi];
            {
                const float y1 = qp[j].x * inv_q * gq[2 * p];
                const float y2 = qp[j].y * inv_q * gq[2 * p + 1];
                *(unsigned*)&qb[(size_t)s * DIM + 2 * p] = pk2bf(y1 * c - y2 * si, y1 * si + y2 * c);
            }
            {
                const float y1 = kp[j].x * inv_k * gk[2 * p];
                const float y2 = kp[j].y * inv_k * gk[2 * p + 1];
                *(unsigned*)&kb[(size_t)s * DIM + 2 * p] = pk2bf(y1 * c - y2 * si, y1 * si + y2 * c);
            }
        }
    } else {
        const int t = bid - SEQ_LEN;
        const int s0 = (t % 49) * 64;
        const int h = t / 49;
        const int rl = tid >> 2, cb = (tid & 3) * 32;
        const int row = min(s0 + rl, SEQ_LEN - 1);
#pragma unroll
        for (int i = 0; i < 4; ++i) {
            const int d = cb + i * 8;
            union { uint4 u; unsigned short t8[8]; } v;
            v.u = *(const uint4*)&qkvb[(size_t)row * QKV_N + 2 * DIM + h * HEAD_DIM + d];
#pragma unroll
            for (int j = 0; j < 8; ++j) T[d + j][rl] = v.t8[j];
        }
        __syncthreads();
        const int od = tid >> 1, ob = (tid & 1) * 32;
        const size_t orow = (size_t)(h * HEAD_DIM + od) * SEQ_LEN;
#pragma unroll
        for (int v8 = 0; v8 < 4; ++v8) {
            const int s = s0 + ob + v8 * 8;
            if (s < SEQ_LEN) {
                union { unsigned short t8[8]; uint4 u; } pk;
#pragma unroll
                for (int j = 0; j < 8; ++j) pk.t8[j] = T[od][ob + v8 * 8 + j];
                *(uint4*)&vt[orow + s] = pk.u;
            }
        }
    }
}

// ---------------------------------------------------------------------------
// Flash attention pass 1 — round-7 structure (cross-chunk st-split pipeline,
// qkt(stN) BEFORE fused sm_pv(stC)). Change vs r9: ONE setprio pair around
// the whole PV loop (was per-kblk — 4 volatile fence pairs/chunk that
// forbade hoisting kblk+1's V ds_reads into kblk's MFMA/permlane shadow).
// permlane32_swap P-exchange; K dbuf + V tribuf; 1 barrier/chunk; Q staged
// with XOR swizzle; direct attb write for 1-split tiles.
// 240 blocks x 512 threads; XCD-pinned heads.
// ---------------------------------------------------------------------------
__global__ __launch_bounds__(512, 2) void attn_part_kernel(
    const unsigned short* __restrict__ qb, const unsigned short* __restrict__ kb,
    const unsigned short* __restrict__ vt, unsigned short* __restrict__ part_o,
    float* __restrict__ part_ml, unsigned short* __restrict__ attb)
{
    __shared__ short KV[40960]; // 80KB: Kbuf 2x8192 shorts @0, Vbuf 3x8192 @16384

    const int bid = blockIdx.x;
    const int xcd = bid & 7;
    const int slot = bid >> 3;   // 0..29
    int h, bx;
    if (slot < 20) { h = xcd; bx = slot; }
    else { h = 8 + (xcd >> 1); bx = (xcd & 1) * 10 + (slot - 20); }

    const int tid = threadIdx.x;
    const int w = tid >> 6;      // 0..7
    const int l = tid & 63;
    int tile, split, nsp;
    if (bx < 6) { tile = bx; split = 0; nsp = 1; }
    else { const int b2 = bx - 6; tile = 6 + (b2 >> 1); split = b2 & 1; nsp = 2; }
    const int q0 = tile * BQ;
    const int lhi = l >> 5;
    const int llo = l & 31;

    // ---- stage Q tile (256 x 128) with XOR swizzle, pull frags ----
#pragma unroll
    for (int s = 0; s < 8; ++s) {
        const int c = (s * 8 + w) * 64 + l;
        const int row = c >> 4, g = c & 15;
        const int gr = min(q0 + row, SEQ_LEN - 1);
        async16(KV + (s * 8 + w) * 512,
                qb + (size_t)gr * DIM + h * HEAD_DIM + (g ^ (row & 7)) * 8);
    }
    __syncthreads();
    short8 qf[8];
#pragma unroll
    for (int ds = 0; ds < 8; ++ds)
        qf[ds] = *(const short8*)&KV[(w * 32 + llo) * 128 +
                                     (((ds * 2 + lhi) ^ (llo & 7)) * 8)];
    __syncthreads();

    const int myq = q0 + w * 32 + llo;
    const int mylimit = (myq < FRAME_LEN) ? FRAME_LEN : SEQ_LEN;
    const int wave_lim = (q0 + w * 32 < FRAME_LEN) ? FRAME_LEN : SEQ_LEN;
    const int Lmax = (tile < 6) ? FRAME_LEN : SEQ_LEN;
    const int nch = (Lmax + 63) >> 6;
    const int kc0 = ((split * nch) / nsp) * 64;
    const int kc1 = (((split + 1) * nch) / nsp) * 64;
    const int nchunks = (kc1 - kc0) >> 6;

    float l_run = 0.f;
    f32x16 o[4];
#pragma unroll
    for (int mt = 0; mt < 4; ++mt)
#pragma unroll
        for (int r = 0; r < 16; ++r) o[mt][r] = 0.f;

    int krloc[2], kcol[2], vcol[2], lof[2];
    size_t vrow[2];
#pragma unroll
    for (int s = 0; s < 2; ++s) {
        const int c = (s * 8 + w) * 64 + l;
        const int kr = c >> 4;
        krloc[s] = kr;
        kcol[s] = h * HEAD_DIM + (((c & 15) ^ (kr & 7)) * 8);
        const int d = c >> 3;
        vrow[s] = (size_t)(h * HEAD_DIM + d) * SEQ_LEN;
        vcol[s] = ((c & 7) ^ (d & 7)) * 8;
        lof[s] = (s * 8 + w) * 512;
    }

    auto issueK = [&](int kc, int b) {
#pragma unroll
        for (int s = 0; s < 2; ++s) {
            const int gr = min(kc + krloc[s], SEQ_LEN - 1);
            async16(KV + b * 8192 + lof[s], kb + (size_t)gr * DIM + kcol[s]);
        }
    };
    auto issueV = [&](int kc, int t) {
#pragma unroll
        for (int s = 0; s < 2; ++s) {
            const int col = min(kc + vcol[s], SEQ_LEN - 8);
            async16(KV + 16384 + t * 8192 + lof[s], vt + vrow[s] + col);
        }
    };

    // S'^T = K Q'^T (Q pre-scaled by log2e/sqrt(hd))
    auto qkt = [&](f32x16* st, int b) {
        const short* Kb = KV + b * 8192;
#pragma unroll
        for (int r = 0; r < 16; ++r) { st[0][r] = 0.f; st[1][r] = 0.f; }
        __builtin_amdgcn_s_setprio(1);
#pragma unroll
        for (int ds = 0; ds < 8; ++ds) {
            const int gd = ds * 2 + lhi;
#pragma unroll
            for (int kt = 0; kt < 2; ++kt) {
                const int krow = kt * 32 + llo;
                short8 kf = *(const short8*)&Kb[krow * 128 + ((gd ^ (krow & 7)) * 8)];
                st[kt] = __builtin_amdgcn_mfma_f32_32x32x16_bf16(kf, qf[ds], st[kt], 0, 0, 0);
            }
        }
        __builtin_amdgcn_s_setprio(0);
    };

    // mask + fixed-max softmax + O^T += V^T P^T for chunk at kc (Vbuf t)
    auto sm_pv = [&](f32x16* st, int kc, int t) {
        if (kc + 64 > wave_lim) {
#pragma unroll
            for (int kt = 0; kt < 2; ++kt)
#pragma unroll
                for (int r = 0; r < 16; ++r) {
                    const int kg = kc + kt * 32 + (r & 3) + 8 * (r >> 2) + 4 * lhi;
                    if (kg >= mylimit) st[kt][r] = -3.0e38f;
                }
        }
        float rsA = 0.f, rsB = 0.f;
        unsigned p16[2][8];
#pragma unroll
        for (int kt = 0; kt < 2; ++kt)
#pragma unroll
            for (int r2 = 0; r2 < 8; ++r2) {
                const float p0 = FEXP2(st[kt][2 * r2] - FMAXC2);
                const float p1 = FEXP2(st[kt][2 * r2 + 1] - FMAXC2);
                if (kt == 0) rsA += p0 + p1; else rsB += p0 + p1;
                p16[kt][r2] = pk2bf(p0, p1);
            }
        l_run += rsA + rsB;

        const short* Vb = KV + 16384 + t * 8192;
        __builtin_amdgcn_s_setprio(1);   // single pair spans all 4 kblk clusters
#pragma unroll
        for (int kblk = 0; kblk < 4; ++kblk) {
            const int tt = kblk >> 1;
            const int i0 = (kblk & 1) * 4;
            union { unsigned u[4]; short8 s8; } pf;
#if __has_builtin(__builtin_amdgcn_permlane32_swap)
            {
                auto s02 = __builtin_amdgcn_permlane32_swap(
                    p16[tt][i0 + 0], p16[tt][i0 + 2], false, false);
                auto s13 = __builtin_amdgcn_permlane32_swap(
                    p16[tt][i0 + 1], p16[tt][i0 + 3], false, false);
                pf.u[0] = s02[0]; pf.u[1] = s13[0];
                pf.u[2] = s02[1]; pf.u[3] = s13[1];
            }
#else
            {
                const int dk    = ((kblk & 1) * 2 + lhi) * 2;
                const int dsend = ((kblk & 1) * 2 + (1 - lhi)) * 2;
                const unsigned r0 = __shfl_xor(p16[tt][dsend], 32);
                const unsigned r1 = __shfl_xor(p16[tt][dsend + 1], 32);
                if (lhi == 0) { pf.u[0] = p16[tt][dk]; pf.u[1] = p16[tt][dk + 1]; pf.u[2] = r0; pf.u[3] = r1; }
                else          { pf.u[0] = r0; pf.u[1] = r1; pf.u[2] = p16[tt][dk]; pf.u[3] = p16[tt][dk + 1]; }
            }
#endif
#pragma unroll
            for (int mt = 0; mt < 4; ++mt) {
                const int vd = mt * 32 + llo;
                short8 vf = *(const short8*)&Vb[vd * 64 + (((kblk * 2 + lhi) ^ (vd & 7)) * 8)];
                o[mt] = __builtin_amdgcn_mfma_f32_32x32x16_bf16(vf, pf.s8, o[mt], 0, 0, 0);
            }
        }
        __builtin_amdgcn_s_setprio(0);
    };

    // ---- pipelined main loop ----
    issueK(kc0, 0); issueV(kc0, 0);
    if (nchunks > 1) { issueK(kc0 + 64, 1); issueV(kc0 + 64, 1); }
    __syncthreads();           // chunk 0 (and 1) staged
    f32x16 stC[2];
    qkt(stC, 0);               // scores for chunk 0 in flight/retired

    int vcur = 0;
    for (int i = 0, kc = kc0; i < nchunks; ++i, kc += 64) {
        __syncthreads();       // chunk i+1 loads visible; frees Kbuf[i&1], Vbuf[(i+2)%3]
        if (i + 2 < nchunks) {
            issueK(kc + 128, i & 1);
            int vt2 = vcur + 2; if (vt2 >= 3) vt2 -= 3;
            issueV(kc + 128, vt2);
        }
        f32x16 stN[2];
        if (i + 1 < nchunks) qkt(stN, (i + 1) & 1);  // next chunk's MFMAs issue now
        sm_pv(stC, kc, vcur);                        // no dependency on stN
        if (i + 1 < nchunks) { stC[0] = stN[0]; stC[1] = stN[1]; }
        vcur = (vcur == 2) ? 0 : vcur + 1;
    }

    // ---- epilogue ----
    const float l_tot = l_run + __shfl_xor(l_run, 32);
    const int qloc = w * 32 + llo;
    const float inv = (l_tot > 0.f) ? 1.0f / l_tot : 0.f;
    if (nsp == 1) {
        unsigned short* op = attb + (size_t)(q0 + qloc) * DIM + h * HEAD_DIM + 4 * lhi;
#pragma unroll
        for (int mt = 0; mt < 4; ++mt)
#pragma unroll
            for (int g = 0; g < 4; ++g) {
                uint2 u;
                u.x = pk2bf(o[mt][4 * g + 0] * inv, o[mt][4 * g + 1] * inv);
                u.y = pk2bf(o[mt][4 * g + 2] * inv, o[mt][4 * g + 3] * inv);
                *(uint2*)&op[mt * 32 + 8 * g] = u;
            }
    } else {
        const int slot_o = bx * HEADS + h;
        unsigned short* op = part_o + (size_t)slot_o * (BQ * HEAD_DIM) + qloc * HEAD_DIM + 4 * lhi;
#pragma unroll
        for (int mt = 0; mt < 4; ++mt)
#pragma unroll
            for (int g = 0; g < 4; ++g) {
                uint2 u;
                u.x = pk2bf(o[mt][4 * g + 0] * inv, o[mt][4 * g + 1] * inv);
                u.y = pk2bf(o[mt][4 * g + 2] * inv, o[mt][4 * g + 3] * inv);
                *(uint2*)&op[mt * 32 + 8 * g] = u;
            }
        if (lhi == 0) part_ml[(size_t)slot_o * BQ + qloc] = l_tot;
    }
}

// ---------------------------------------------------------------------------
// Combine pass (2-split tiles only, q >= 1536): weights = l_s -> attb bf16.
// ---------------------------------------------------------------------------
__global__ __launch_bounds__(256) void attn_combine_kernel(
    const unsigned short* __restrict__ part_o, const float* __restrict__ part_ml,
    unsigned short* __restrict__ attb)
{
    const int h = blockIdx.y;
    const int q = 1536 + blockIdx.x * 8 + (threadIdx.x >> 5);
    const int dq = (threadIdx.x & 31) * 4;
    const int tile = q >> 8, qloc = q & 255;
    const int base_bx = 6 + (tile - 6) * 2;

    float W = 0.f;
    float acc[4] = {0.f, 0.f, 0.f, 0.f};
#pragma unroll
    for (int s = 0; s < 2; ++s) {
        const int slot = (base_bx + s) * HEADS + h;
        const float w = part_ml[(size_t)slot * BQ + qloc];
        if (w > 0.f) {
            W += w;
            const unsigned short* po = part_o +
                (size_t)slot * (BQ * HEAD_DIM) + qloc * HEAD_DIM + dq;
            uint2 u = *(const uint2*)po;
            acc[0] += w * bf2f((unsigned short)(u.x & 0xffff));
            acc[1] += w * bf2f((unsigned short)(u.x >> 16));
            acc[2] += w * bf2f((unsigned short)(u.y & 0xffff));
            acc[3] += w * bf2f((unsigned short)(u.y >> 16));
        }
    }
    const float inv = 1.0f / W;
    uint2 pk;
    pk.x = pk2bf(acc[0] * inv, acc[1] * inv);
    pk.y = pk2bf(acc[2] * inv, acc[3] * inv);
    *(uint2*)&attb[(size_t)q * DIM + h * HEAD_DIM + dq] = pk;
}

// ---------------------------------------------------------------------------
extern "C" void kernel_launch(void* const* d_in, const int* in_sizes, int n_in,
                              void* d_out, int out_size, void* d_ws, size_t ws_size,
                              hipStream_t stream)
{
    const float* hs    = (const float*)d_in[0];
    const float* cosf  = (const float*)d_in[1];
    const float* sinf  = (const float*)d_in[2];
    const float* w_qkv = (const float*)d_in[3];
    const float* b_qkv = (const float*)d_in[4];
    const float* g_q   = (const float*)d_in[5];
    const float* g_k   = (const float*)d_in[6];
    const float* w_out = (const float*)d_in[7];
    const float* b_out = (const float*)d_in[8];

    // workspace layout (same offsets; part_o = 240 slots x 256 x 128 bf16).
    char* base = (char*)d_ws;
    unsigned short* qb     = (unsigned short*)base;                //  9,584,640
    unsigned short* kb     = (unsigned short*)(base + 9584640);    //  9,584,640
    unsigned short* vt     = (unsigned short*)(base + 19169280);   //  9,584,640 (alias hsb)
    unsigned short* hsb    = vt;
    unsigned short* qkvb   = (unsigned short*)(base + 28753920);   // 28,753,920
    unsigned short* part_o = (unsigned short*)(base + 28753920);   // 15,728,640 (alias qkvb)
    float*          part_ml= (float*)(base + 60211200);            //    245,760 (alias qkvb)
    unsigned short* wqkvT  = (unsigned short*)(base + 81469440);   // 14,155,776 (alias attb)
    unsigned short* attb   = wqkvT;
    unsigned short* woutT  = (unsigned short*)(base + 95625216);   //  4,718,592
    float* outp = (float*)d_out;

    // 1) fused prep: hs->bf16 + both weight transposes (one launch)
    prep_kernel<<<4644, 256, 0, stream>>>(hs, hsb, w_qkv, wqkvT, w_out, woutT);
    // 2) qkvb = hs @ w_qkv + b_qkv (bf16 out), 256^2 pipelined tile
    gemm256_bf16_kernel<<<234, 512, 0, stream>>>(
        hsb, wqkvT, b_qkv, qkvb, SEQ_LEN, QKV_N, DIM);
    // 3) fused rmsnorm+rope (-> qb,kb) and v-transpose (-> vt), one launch
    rope_vt_kernel<<<SEQ_LEN + 49 * HEADS, 256, 0, stream>>>(
        qkvb, g_q, g_k, cosf, sinf, qb, kb, vt);
    // 4) attention pass 1: 240 blocks x 512 threads; frame-1 tiles -> attb direct
    attn_part_kernel<<<240, 512, 0, stream>>>(qb, kb, vt, part_o, part_ml, attb);
    // 5) combine (q >= 1536 only) -> attb bf16 [s][h*128+d]
    attn_combine_kernel<<<dim3((SEQ_LEN - 1536) / 8, HEADS), 256, 0, stream>>>(
        part_o, part_ml, attb);
    // 6) out = attb @ w_out + b_out (fp32), 128^2 BK=64 pipelined tile (300 blocks)
    gemm128_f32_kernel<<<304, 256, 0, stream>>>(
        attb, woutT, b_out, outp, SEQ_LEN, DIM, DIM);
}

// Round 11
// 267.182 us; speedup vs baseline: 1.0032x; 1.0032x over previous
//
#include <hip/hip_runtime.h>
#include <hip/hip_bf16.h>
#include <stdint.h>

#define SEQ_LEN 3120
#define DIM 1536
#define QKV_N 4608
#define HEADS 12
#define HEAD_DIM 128
#define FRAME_LEN 1560
#define SM_SCALE 0.08838834764831845f   // 1/sqrt(128)
#define LOG2E 1.4426950408889634f
#define FMAXC2 43.280851226669165f      // 30*log2e; p = 2^(s' - 43.28), s' = s*log2e
#define BQ 256                           // q rows per attention block (8 waves x 32)

#if __has_builtin(__builtin_amdgcn_exp2f)
#define FEXP2(x) __builtin_amdgcn_exp2f(x)
#else
#define FEXP2(x) exp2f(x)
#endif

typedef short short8 __attribute__((ext_vector_type(8)));
typedef float f32x4 __attribute__((ext_vector_type(4)));
typedef float f32x16 __attribute__((ext_vector_type(16)));

__device__ __forceinline__ unsigned short f2bf(float x) {
    union { float f; unsigned u; } v; v.f = x;
    unsigned r = v.u + 0x7fffu + ((v.u >> 16) & 1u);
    return (unsigned short)(r >> 16);
}
__device__ __forceinline__ float bf2f(unsigned short b) {
    union { unsigned u; float f; } v; v.u = ((unsigned)b) << 16;
    return v.f;
}
__device__ __forceinline__ unsigned pk2bf(float a, float b) {
    __hip_bfloat162 h = __float22bfloat162_rn(make_float2(a, b));
    union { __hip_bfloat162 h2; unsigned u; } v; v.h2 = h;
    return v.u;
}

__device__ __forceinline__ void async16(void* lds, const void* g) {
    __builtin_amdgcn_global_load_lds(
        (const __attribute__((address_space(1))) unsigned int*)g,
        (__attribute__((address_space(3))) unsigned int*)lds, 16, 0, 0);
}

// ---------------------------------------------------------------------------
// Fused prep: hs->bf16 convert (blocks 0..2339), w_qkv transpose (2340..4067),
// w_out transpose (4068..4643). One launch instead of three.
// ---------------------------------------------------------------------------
__device__ __forceinline__ void transpose_tile(
    const float* __restrict__ in, unsigned short* __restrict__ out,
    int R, int C, int c0, int r0, float (*T)[65], int tid)
{
    const int rl = tid >> 4, cl = (tid & 15) * 4;
#pragma unroll
    for (int i = 0; i < 4; ++i) {
        const int row = r0 + rl + i * 16;
        float4 v = *(const float4*)&in[(size_t)row * C + c0 + cl];
        T[cl + 0][rl + i * 16] = v.x; T[cl + 1][rl + i * 16] = v.y;
        T[cl + 2][rl + i * 16] = v.z; T[cl + 3][rl + i * 16] = v.w;
    }
    __syncthreads();
    const int oc = tid >> 2, ob = (tid & 3) * 16;
    union { unsigned short t[16]; uint4 u[2]; } p;
#pragma unroll
    for (int j = 0; j < 16; ++j) p.t[j] = f2bf(T[oc][ob + j]);
    uint4* dst = (uint4*)&out[(size_t)(c0 + oc) * R + r0 + ob];
    dst[0] = p.u[0];
    dst[1] = p.u[1];
}

__global__ __launch_bounds__(256) void prep_kernel(
    const float* __restrict__ hs, unsigned short* __restrict__ hsb,
    const float* __restrict__ w_qkv, unsigned short* __restrict__ wqkvT,
    const float* __restrict__ w_out, unsigned short* __restrict__ woutT)
{
    __shared__ float T[64][65];
    const int bid = blockIdx.x;
    const int tid = threadIdx.x;
    if (bid < 2340) {
        const int i = bid * 256 + tid;
        const float4 a = ((const float4*)hs)[i * 2];
        const float4 b = ((const float4*)hs)[i * 2 + 1];
        union { unsigned short t[8]; uint4 u; } p;
        p.t[0] = f2bf(a.x); p.t[1] = f2bf(a.y); p.t[2] = f2bf(a.z); p.t[3] = f2bf(a.w);
        p.t[4] = f2bf(b.x); p.t[5] = f2bf(b.y); p.t[6] = f2bf(b.z); p.t[7] = f2bf(b.w);
        ((uint4*)hsb)[i] = p.u;
    } else if (bid < 4068) {
        const int t = bid - 2340; // 72 x 24 tiles of w_qkv [1536][4608]
        transpose_tile(w_qkv, wqkvT, DIM, QKV_N, (t % 72) * 64, (t / 72) * 64, T, tid);
    } else {
        const int t = bid - 4068; // 24 x 24 tiles of w_out [1536][1536]
        transpose_tile(w_out, woutT, DIM, DIM, (t % 24) * 64, (t / 24) * 64, T, tid);
    }
}

// ---------------------------------------------------------------------------
// 128^2-tile fp32-out GEMM (output projection), gemm256 schedule ported:
// BK=64, 4 waves (2Mx2N), 64KB LDS double-buffer, both-sides XOR swizzle,
// issue-early staging, single raw vmcnt(0)+s_barrier per K-tile, setprio.
// Grid: bijective n-major chunked XCD mapping over 25x12=300 tiles.
// ---------------------------------------------------------------------------
__global__ __launch_bounds__(256, 2) void gemm128_f32_kernel(
    const unsigned short* __restrict__ A, const unsigned short* __restrict__ Bt,
    const float* __restrict__ bias, float* __restrict__ C, int M, int N, int K)
{
    __shared__ short LDS[32768]; // [A0 8192 | B0 8192 | A1 8192 | B1 8192]

    const int mtiles = (M + 127) >> 7;
    const int nwg = mtiles * (N >> 7);
    const int q = nwg >> 3, r = nwg & 7;
    const int xcd = blockIdx.x & 7;
    const int cnt = q + (xcd < r ? 1 : 0);
    const int li = blockIdx.x >> 3;
    if (li >= cnt) return;
    const int g0 = (xcd < r) ? xcd * (q + 1) : r * (q + 1) + (xcd - r) * q;
    const int g = g0 + li;
    const int m0 = (g % mtiles) * 128;
    const int n0 = (g / mtiles) * 128;

    const int tid = threadIdx.x;
    const int w = tid >> 6, l = tid & 63;
    const int wr = w >> 1, wc = w & 1;         // 2 x 2 wave grid
    const int lhi = l >> 4, llo = l & 15;

    f32x4 acc[4][4];
#pragma unroll
    for (int i = 0; i < 4; ++i)
#pragma unroll
        for (int j = 0; j < 4; ++j) acc[i][j] = f32x4{0.f, 0.f, 0.f, 0.f};

    const unsigned short* gsrc[8];
#pragma unroll
    for (int j = 0; j < 4; ++j) {
        const int c = (j * 4 + w) * 64 + l;
        const int row = c >> 3, ks = c & 7;
        gsrc[j] = A + (size_t)min(m0 + row, M - 1) * K + (ks ^ (row & 7)) * 8;
    }
#pragma unroll
    for (int j = 0; j < 4; ++j) {
        const int c = (j * 4 + w) * 64 + l;
        const int row = c >> 3, ks = c & 7;
        gsrc[4 + j] = Bt + (size_t)min(n0 + row, N - 1) * K + (ks ^ (row & 7)) * 8;
    }

    auto stageAll = [&](int kt, int b) {
        short* dst = LDS + b * 16384;
#pragma unroll
        for (int j = 0; j < 4; ++j)
            async16(dst + (j * 4 + w) * 512, gsrc[j] + kt * 64);
#pragma unroll
        for (int j = 0; j < 4; ++j)
            async16(dst + 8192 + (j * 4 + w) * 512, gsrc[4 + j] + kt * 64);
    };

    const int nk = K >> 6;
    stageAll(0, 0);
    asm volatile("s_waitcnt vmcnt(0)\n\ts_barrier" ::: "memory");

    for (int t = 0; t < nk; ++t) {
        if (t + 1 < nk) stageAll(t + 1, (t + 1) & 1);   // issue early
        const short* Ab = LDS + (t & 1) * 16384;
        const short* Bb = Ab + 8192;
#pragma unroll
        for (int ph = 0; ph < 2; ++ph) {                // k-step = ph*32
            short8 bfr[4], afr[4];
#pragma unroll
            for (int nt = 0; nt < 4; ++nt) {
                const int rb = wc * 64 + nt * 16 + llo;
                bfr[nt] = *(const short8*)&Bb[rb * 64 + ((ph * 4 + lhi) ^ (rb & 7)) * 8];
            }
#pragma unroll
            for (int mt = 0; mt < 4; ++mt) {
                const int ra = wr * 64 + mt * 16 + llo;
                afr[mt] = *(const short8*)&Ab[ra * 64 + ((ph * 4 + lhi) ^ (ra & 7)) * 8];
            }
            __builtin_amdgcn_s_setprio(1);
#pragma unroll
            for (int mt = 0; mt < 4; ++mt)
#pragma unroll
                for (int nt = 0; nt < 4; ++nt)
                    acc[mt][nt] = __builtin_amdgcn_mfma_f32_16x16x32_bf16(
                        afr[mt], bfr[nt], acc[mt][nt], 0, 0, 0);
            __builtin_amdgcn_s_setprio(0);
        }
        asm volatile("s_waitcnt vmcnt(0)\n\ts_barrier" ::: "memory");
    }

#pragma unroll
    for (int mt = 0; mt < 4; ++mt)
#pragma unroll
        for (int ri = 0; ri < 4; ++ri) {
            const int row = m0 + wr * 64 + mt * 16 + lhi * 4 + ri;
            if (row < M) {
#pragma unroll
                for (int nt = 0; nt < 4; ++nt) {
                    const int col = n0 + wc * 64 + nt * 16 + llo;
                    C[(size_t)row * N + col] = acc[mt][nt][ri] + bias[col];
                }
            }
        }
}

// ---------------------------------------------------------------------------
// 256^2-tile bf16 GEMM (qkv projection). BK=64, 8 waves (2Mx4N), 128KB LDS
// double-buffer, T2 swizzle (both-sides), issue-early/drain-late, raw
// vmcnt(0)+s_barrier once per K-tile, s_setprio around MFMA clusters.
// ---------------------------------------------------------------------------
__global__ __launch_bounds__(512, 2) void gemm256_bf16_kernel(
    const unsigned short* __restrict__ A, const unsigned short* __restrict__ Bt,
    const float* __restrict__ bias, unsigned short* __restrict__ C,
    int M, int N, int K)
{
    __shared__ short LDS[65536]; // [A0 | B0 | A1 | B1] x 16384 shorts

    const int mtiles = (M + 255) >> 8;
    const int nwg = mtiles * (N >> 8);
    const int q = nwg >> 3, r = nwg & 7;
    const int xcd = blockIdx.x & 7;
    const int g0 = (xcd < r) ? xcd * (q + 1) : r * (q + 1) + (xcd - r) * q;
    const int g = g0 + (int)(blockIdx.x >> 3);
    const int m0 = (g % mtiles) * 256;
    const int n0 = (g / mtiles) * 256;

    const int tid = threadIdx.x;
    const int w = tid >> 6, l = tid & 63;
    const int wr = w >> 2, wc = w & 3;          // 2 x 4 wave grid
    const int lhi = l >> 4, llo = l & 15;

    f32x4 acc[8][4];
#pragma unroll
    for (int i = 0; i < 8; ++i)
#pragma unroll
        for (int j = 0; j < 4; ++j) acc[i][j] = f32x4{0.f, 0.f, 0.f, 0.f};

    const unsigned short* gsrc[8];
#pragma unroll
    for (int j = 0; j < 4; ++j) {
        const int c = (j * 8 + w) * 64 + l;
        const int row = c >> 3, ks = c & 7;
        gsrc[j] = A + (size_t)min(m0 + row, M - 1) * K + (ks ^ (row & 7)) * 8;
    }
#pragma unroll
    for (int j = 0; j < 4; ++j) {
        const int c = (j * 8 + w) * 64 + l;
        const int row = c >> 3, ks = c & 7;
        gsrc[4 + j] = Bt + (size_t)min(n0 + row, N - 1) * K + (ks ^ (row & 7)) * 8;
    }

    auto stageAll = [&](int kt, int b) {
        short* dst = LDS + b * 32768;
#pragma unroll
        for (int j = 0; j < 4; ++j)
            async16(dst + (j * 8 + w) * 512, gsrc[j] + kt * 64);
#pragma unroll
        for (int j = 0; j < 4; ++j)
            async16(dst + 16384 + (j * 8 + w) * 512, gsrc[4 + j] + kt * 64);
    };

    const int nk = K >> 6;
    stageAll(0, 0);
    asm volatile("s_waitcnt vmcnt(0)\n\ts_barrier" ::: "memory");

    for (int t = 0; t < nk; ++t) {
        if (t + 1 < nk) stageAll(t + 1, (t + 1) & 1);   // issue early
        const short* Ab = LDS + (t & 1) * 32768;
        const short* Bb = Ab + 16384;
#pragma unroll
        for (int ph = 0; ph < 2; ++ph) {                // k-step = ph*32
            short8 bfr[4];
#pragma unroll
            for (int nt = 0; nt < 4; ++nt) {
                const int rb = wc * 64 + nt * 16 + llo;
                bfr[nt] = *(const short8*)&Bb[rb * 64 + ((ph * 4 + lhi) ^ (rb & 7)) * 8];
            }
#pragma unroll
            for (int mh = 0; mh < 2; ++mh) {
                short8 afr[4];
#pragma unroll
                for (int mt = 0; mt < 4; ++mt) {
                    const int ra = wr * 128 + mh * 64 + mt * 16 + llo;
                    afr[mt] = *(const short8*)&Ab[ra * 64 + ((ph * 4 + lhi) ^ (ra & 7)) * 8];
                }
                __builtin_amdgcn_s_setprio(1);
#pragma unroll
                for (int mt = 0; mt < 4; ++mt)
#pragma unroll
                    for (int nt = 0; nt < 4; ++nt)
                        acc[mh * 4 + mt][nt] = __builtin_amdgcn_mfma_f32_16x16x32_bf16(
                            afr[mt], bfr[nt], acc[mh * 4 + mt][nt], 0, 0, 0);
                __builtin_amdgcn_s_setprio(0);
            }
        }
        asm volatile("s_waitcnt vmcnt(0)\n\ts_barrier" ::: "memory");
    }

#pragma unroll
    for (int mi = 0; mi < 8; ++mi)
#pragma unroll
        for (int ri = 0; ri < 4; ++ri) {
            const int row = m0 + wr * 128 + mi * 16 + lhi * 4 + ri;
            if (row < M) {
#pragma unroll
                for (int nt = 0; nt < 4; ++nt) {
                    const int col = n0 + wc * 64 + nt * 16 + llo;
                    C[(size_t)row * N + col] = f2bf(acc[mi][nt][ri] + bias[col]);
                }
            }
        }
}

// ---------------------------------------------------------------------------
// Fused RMSNorm+RoPE (blocks 0..3119) and V-transpose (blocks 3120..3707).
// ---------------------------------------------------------------------------
__global__ __launch_bounds__(256) void rope_vt_kernel(
    const unsigned short* __restrict__ qkvb, const float* __restrict__ gq,
    const float* __restrict__ gk, const float* __restrict__ cosf,
    const float* __restrict__ sinf, unsigned short* __restrict__ qb,
    unsigned short* __restrict__ kb, unsigned short* __restrict__ vt)
{
    __shared__ unsigned short T[128][72];
    __shared__ float wq[4], wk[4];
    const int bid = blockIdx.x;
    const int tid = threadIdx.x;

    if (bid < SEQ_LEN) {
        const int s = bid;
        const unsigned short* qrow = qkvb + (size_t)s * QKV_N;
        const unsigned short* krow = qrow + DIM;

        float2 qp[3], kp[3];
        float ssq_q = 0.f, ssq_k = 0.f;
#pragma unroll
        for (int j = 0; j < 3; ++j) {
            const int p = tid + j * 256;
            const unsigned uq = *(const unsigned*)(qrow + 2 * p);
            const unsigned uk = *(const unsigned*)(krow + 2 * p);
            qp[j] = make_float2(bf2f((unsigned short)(uq & 0xffff)), bf2f((unsigned short)(uq >> 16)));
            kp[j] = make_float2(bf2f((unsigned short)(uk & 0xffff)), bf2f((unsigned short)(uk >> 16)));
            ssq_q += qp[j].x * qp[j].x + qp[j].y * qp[j].y;
            ssq_k += kp[j].x * kp[j].x + kp[j].y * kp[j].y;
        }
#pragma unroll
        for (int off = 32; off > 0; off >>= 1) {
            ssq_q += __shfl_down(ssq_q, off);
            ssq_k += __shfl_down(ssq_k, off);
        }
        const int wave = tid >> 6, lane = tid & 63;
        if (lane == 0) { wq[wave] = ssq_q; wk[wave] = ssq_k; }
        __syncthreads();
        const float tq = wq[0] + wq[1] + wq[2] + wq[3];
        const float tk = wk[0] + wk[1] + wk[2] + wk[3];
        const float inv_q = rsqrtf(tq * (1.0f / DIM) + 1e-6f) * (SM_SCALE * LOG2E);
        const float inv_k = rsqrtf(tk * (1.0f / DIM) + 1e-6f);

#pragma unroll
        for (int j = 0; j < 3; ++j) {
            const int p = tid + j * 256;
            const int fi = p & 63;
            const float c = cosf[s * 64 + fi];
            const float si = sinf[s * 64 + fi];
            {
                const float y1 = qp[j].x * inv_q * gq[2 * p];
                const float y2 = qp[j].y * inv_q * gq[2 * p + 1];
                *(unsigned*)&qb[(size_t)s * DIM + 2 * p] = pk2bf(y1 * c - y2 * si, y1 * si + y2 * c);
            }
            {
                const float y1 = kp[j].x * inv_k * gk[2 * p];
                const float y2 = kp[j].y * inv_k * gk[2 * p + 1];
                *(unsigned*)&kb[(size_t)s * DIM + 2 * p] = pk2bf(y1 * c - y2 * si, y1 * si + y2 * c);
            }
        }
    } else {
        const int t = bid - SEQ_LEN;
        const int s0 = (t % 49) * 64;
        const int h = t / 49;
        const int rl = tid >> 2, cb = (tid & 3) * 32;
        const int row = min(s0 + rl, SEQ_LEN - 1);
#pragma unroll
        for (int i = 0; i < 4; ++i) {
            const int d = cb + i * 8;
            union { uint4 u; unsigned short t8[8]; } v;
            v.u = *(const uint4*)&qkvb[(size_t)row * QKV_N + 2 * DIM + h * HEAD_DIM + d];
#pragma unroll
            for (int j = 0; j < 8; ++j) T[d + j][rl] = v.t8[j];
        }
        __syncthreads();
        const int od = tid >> 1, ob = (tid & 1) * 32;
        const size_t orow = (size_t)(h * HEAD_DIM + od) * SEQ_LEN;
#pragma unroll
        for (int v8 = 0; v8 < 4; ++v8) {
            const int s = s0 + ob + v8 * 8;
            if (s < SEQ_LEN) {
                union { unsigned short t8[8]; uint4 u; } pk;
#pragma unroll
                for (int j = 0; j < 8; ++j) pk.t8[j] = T[od][ob + v8 * 8 + j];
                *(uint4*)&vt[orow + s] = pk.u;
            }
        }
    }
}

// ---------------------------------------------------------------------------
// Flash attention pass 1 — round-9 structure restored exactly (session best:
// cross-chunk st-split pipeline, qkt(stN) BEFORE fused sm_pv(stC), PER-KBLK
// setprio in PV — r10's single-span variant was +3.6us: the setprio(0) gaps
// between clusters let the co-resident block's MFMA waves claim the SIMD
// during this wave's permlane/VALU segments). permlane32_swap P-exchange;
// K dbuf + V tribuf; 1 barrier/chunk; Q staged with XOR swizzle; direct
// attb write for 1-split tiles. 240 blocks x 512 threads; XCD-pinned heads.
// ---------------------------------------------------------------------------
__global__ __launch_bounds__(512, 2) void attn_part_kernel(
    const unsigned short* __restrict__ qb, const unsigned short* __restrict__ kb,
    const unsigned short* __restrict__ vt, unsigned short* __restrict__ part_o,
    float* __restrict__ part_ml, unsigned short* __restrict__ attb)
{
    __shared__ short KV[40960]; // 80KB: Kbuf 2x8192 shorts @0, Vbuf 3x8192 @16384

    const int bid = blockIdx.x;
    const int xcd = bid & 7;
    const int slot = bid >> 3;   // 0..29
    int h, bx;
    if (slot < 20) { h = xcd; bx = slot; }
    else { h = 8 + (xcd >> 1); bx = (xcd & 1) * 10 + (slot - 20); }

    const int tid = threadIdx.x;
    const int w = tid >> 6;      // 0..7
    const int l = tid & 63;
    int tile, split, nsp;
    if (bx < 6) { tile = bx; split = 0; nsp = 1; }
    else { const int b2 = bx - 6; tile = 6 + (b2 >> 1); split = b2 & 1; nsp = 2; }
    const int q0 = tile * BQ;
    const int lhi = l >> 5;
    const int llo = l & 31;

    // ---- stage Q tile (256 x 128) with XOR swizzle, pull frags ----
#pragma unroll
    for (int s = 0; s < 8; ++s) {
        const int c = (s * 8 + w) * 64 + l;
        const int row = c >> 4, g = c & 15;
        const int gr = min(q0 + row, SEQ_LEN - 1);
        async16(KV + (s * 8 + w) * 512,
                qb + (size_t)gr * DIM + h * HEAD_DIM + (g ^ (row & 7)) * 8);
    }
    __syncthreads();
    short8 qf[8];
#pragma unroll
    for (int ds = 0; ds < 8; ++ds)
        qf[ds] = *(const short8*)&KV[(w * 32 + llo) * 128 +
                                     (((ds * 2 + lhi) ^ (llo & 7)) * 8)];
    __syncthreads();

    const int myq = q0 + w * 32 + llo;
    const int mylimit = (myq < FRAME_LEN) ? FRAME_LEN : SEQ_LEN;
    const int wave_lim = (q0 + w * 32 < FRAME_LEN) ? FRAME_LEN : SEQ_LEN;
    const int Lmax = (tile < 6) ? FRAME_LEN : SEQ_LEN;
    const int nch = (Lmax + 63) >> 6;
    const int kc0 = ((split * nch) / nsp) * 64;
    const int kc1 = (((split + 1) * nch) / nsp) * 64;
    const int nchunks = (kc1 - kc0) >> 6;

    float l_run = 0.f;
    f32x16 o[4];
#pragma unroll
    for (int mt = 0; mt < 4; ++mt)
#pragma unroll
        for (int r = 0; r < 16; ++r) o[mt][r] = 0.f;

    int krloc[2], kcol[2], vcol[2], lof[2];
    size_t vrow[2];
#pragma unroll
    for (int s = 0; s < 2; ++s) {
        const int c = (s * 8 + w) * 64 + l;
        const int kr = c >> 4;
        krloc[s] = kr;
        kcol[s] = h * HEAD_DIM + (((c & 15) ^ (kr & 7)) * 8);
        const int d = c >> 3;
        vrow[s] = (size_t)(h * HEAD_DIM + d) * SEQ_LEN;
        vcol[s] = ((c & 7) ^ (d & 7)) * 8;
        lof[s] = (s * 8 + w) * 512;
    }

    auto issueK = [&](int kc, int b) {
#pragma unroll
        for (int s = 0; s < 2; ++s) {
            const int gr = min(kc + krloc[s], SEQ_LEN - 1);
            async16(KV + b * 8192 + lof[s], kb + (size_t)gr * DIM + kcol[s]);
        }
    };
    auto issueV = [&](int kc, int t) {
#pragma unroll
        for (int s = 0; s < 2; ++s) {
            const int col = min(kc + vcol[s], SEQ_LEN - 8);
            async16(KV + 16384 + t * 8192 + lof[s], vt + vrow[s] + col);
        }
    };

    // S'^T = K Q'^T (Q pre-scaled by log2e/sqrt(hd))
    auto qkt = [&](f32x16* st, int b) {
        const short* Kb = KV + b * 8192;
#pragma unroll
        for (int r = 0; r < 16; ++r) { st[0][r] = 0.f; st[1][r] = 0.f; }
        __builtin_amdgcn_s_setprio(1);
#pragma unroll
        for (int ds = 0; ds < 8; ++ds) {
            const int gd = ds * 2 + lhi;
#pragma unroll
            for (int kt = 0; kt < 2; ++kt) {
                const int krow = kt * 32 + llo;
                short8 kf = *(const short8*)&Kb[krow * 128 + ((gd ^ (krow & 7)) * 8)];
                st[kt] = __builtin_amdgcn_mfma_f32_32x32x16_bf16(kf, qf[ds], st[kt], 0, 0, 0);
            }
        }
        __builtin_amdgcn_s_setprio(0);
    };

    // mask + fixed-max softmax + O^T += V^T P^T for chunk at kc (Vbuf t)
    auto sm_pv = [&](f32x16* st, int kc, int t) {
        if (kc + 64 > wave_lim) {
#pragma unroll
            for (int kt = 0; kt < 2; ++kt)
#pragma unroll
                for (int r = 0; r < 16; ++r) {
                    const int kg = kc + kt * 32 + (r & 3) + 8 * (r >> 2) + 4 * lhi;
                    if (kg >= mylimit) st[kt][r] = -3.0e38f;
                }
        }
        float rsA = 0.f, rsB = 0.f;
        unsigned p16[2][8];
#pragma unroll
        for (int kt = 0; kt < 2; ++kt)
#pragma unroll
            for (int r2 = 0; r2 < 8; ++r2) {
                const float p0 = FEXP2(st[kt][2 * r2] - FMAXC2);
                const float p1 = FEXP2(st[kt][2 * r2 + 1] - FMAXC2);
                if (kt == 0) rsA += p0 + p1; else rsB += p0 + p1;
                p16[kt][r2] = pk2bf(p0, p1);
            }
        l_run += rsA + rsB;

        const short* Vb = KV + 16384 + t * 8192;
#pragma unroll
        for (int kblk = 0; kblk < 4; ++kblk) {
            const int tt = kblk >> 1;
            const int i0 = (kblk & 1) * 4;
            union { unsigned u[4]; short8 s8; } pf;
#if __has_builtin(__builtin_amdgcn_permlane32_swap)
            {
                auto s02 = __builtin_amdgcn_permlane32_swap(
                    p16[tt][i0 + 0], p16[tt][i0 + 2], false, false);
                auto s13 = __builtin_amdgcn_permlane32_swap(
                    p16[tt][i0 + 1], p16[tt][i0 + 3], false, false);
                pf.u[0] = s02[0]; pf.u[1] = s13[0];
                pf.u[2] = s02[1]; pf.u[3] = s13[1];
            }
#else
            {
                const int dk    = ((kblk & 1) * 2 + lhi) * 2;
                const int dsend = ((kblk & 1) * 2 + (1 - lhi)) * 2;
                const unsigned r0 = __shfl_xor(p16[tt][dsend], 32);
                const unsigned r1 = __shfl_xor(p16[tt][dsend + 1], 32);
                if (lhi == 0) { pf.u[0] = p16[tt][dk]; pf.u[1] = p16[tt][dk + 1]; pf.u[2] = r0; pf.u[3] = r1; }
                else          { pf.u[0] = r0; pf.u[1] = r1; pf.u[2] = p16[tt][dk]; pf.u[3] = p16[tt][dk + 1]; }
            }
#endif
            __builtin_amdgcn_s_setprio(1);
#pragma unroll
            for (int mt = 0; mt < 4; ++mt) {
                const int vd = mt * 32 + llo;
                short8 vf = *(const short8*)&Vb[vd * 64 + (((kblk * 2 + lhi) ^ (vd & 7)) * 8)];
                o[mt] = __builtin_amdgcn_mfma_f32_32x32x16_bf16(vf, pf.s8, o[mt], 0, 0, 0);
            }
            __builtin_amdgcn_s_setprio(0);
        }
    };

    // ---- pipelined main loop ----
    issueK(kc0, 0); issueV(kc0, 0);
    if (nchunks > 1) { issueK(kc0 + 64, 1); issueV(kc0 + 64, 1); }
    __syncthreads();           // chunk 0 (and 1) staged
    f32x16 stC[2];
    qkt(stC, 0);               // scores for chunk 0 in flight/retired

    int vcur = 0;
    for (int i = 0, kc = kc0; i < nchunks; ++i, kc += 64) {
        __syncthreads();       // chunk i+1 loads visible; frees Kbuf[i&1], Vbuf[(i+2)%3]
        if (i + 2 < nchunks) {
            issueK(kc + 128, i & 1);
            int vt2 = vcur + 2; if (vt2 >= 3) vt2 -= 3;
            issueV(kc + 128, vt2);
        }
        f32x16 stN[2];
        if (i + 1 < nchunks) qkt(stN, (i + 1) & 1);  // next chunk's MFMAs issue now
        sm_pv(stC, kc, vcur);                        // no dependency on stN
        if (i + 1 < nchunks) { stC[0] = stN[0]; stC[1] = stN[1]; }
        vcur = (vcur == 2) ? 0 : vcur + 1;
    }

    // ---- epilogue ----
    const float l_tot = l_run + __shfl_xor(l_run, 32);
    const int qloc = w * 32 + llo;
    const float inv = (l_tot > 0.f) ? 1.0f / l_tot : 0.f;
    if (nsp == 1) {
        unsigned short* op = attb + (size_t)(q0 + qloc) * DIM + h * HEAD_DIM + 4 * lhi;
#pragma unroll
        for (int mt = 0; mt < 4; ++mt)
#pragma unroll
            for (int g = 0; g < 4; ++g) {
                uint2 u;
                u.x = pk2bf(o[mt][4 * g + 0] * inv, o[mt][4 * g + 1] * inv);
                u.y = pk2bf(o[mt][4 * g + 2] * inv, o[mt][4 * g + 3] * inv);
                *(uint2*)&op[mt * 32 + 8 * g] = u;
            }
    } else {
        const int slot_o = bx * HEADS + h;
        unsigned short* op = part_o + (size_t)slot_o * (BQ * HEAD_DIM) + qloc * HEAD_DIM + 4 * lhi;
#pragma unroll
        for (int mt = 0; mt < 4; ++mt)
#pragma unroll
            for (int g = 0; g < 4; ++g) {
                uint2 u;
                u.x = pk2bf(o[mt][4 * g + 0] * inv, o[mt][4 * g + 1] * inv);
                u.y = pk2bf(o[mt][4 * g + 2] * inv, o[mt][4 * g + 3] * inv);
                *(uint2*)&op[mt * 32 + 8 * g] = u;
            }
        if (lhi == 0) part_ml[(size_t)slot_o * BQ + qloc] = l_tot;
    }
}

// ---------------------------------------------------------------------------
// Combine pass (2-split tiles only, q >= 1536): weights = l_s -> attb bf16.
// ---------------------------------------------------------------------------
__global__ __launch_bounds__(256) void attn_combine_kernel(
    const unsigned short* __restrict__ part_o, const float* __restrict__ part_ml,
    unsigned short* __restrict__ attb)
{
    const int h = blockIdx.y;
    const int q = 1536 + blockIdx.x * 8 + (threadIdx.x >> 5);
    const int dq = (threadIdx.x & 31) * 4;
    const int tile = q >> 8, qloc = q & 255;
    const int base_bx = 6 + (tile - 6) * 2;

    float W = 0.f;
    float acc[4] = {0.f, 0.f, 0.f, 0.f};
#pragma unroll
    for (int s = 0; s < 2; ++s) {
        const int slot = (base_bx + s) * HEADS + h;
        const float w = part_ml[(size_t)slot * BQ + qloc];
        if (w > 0.f) {
            W += w;
            const unsigned short* po = part_o +
                (size_t)slot * (BQ * HEAD_DIM) + qloc * HEAD_DIM + dq;
            uint2 u = *(const uint2*)po;
            acc[0] += w * bf2f((unsigned short)(u.x & 0xffff));
            acc[1] += w * bf2f((unsigned short)(u.x >> 16));
            acc[2] += w * bf2f((unsigned short)(u.y & 0xffff));
            acc[3] += w * bf2f((unsigned short)(u.y >> 16));
        }
    }
    const float inv = 1.0f / W;
    uint2 pk;
    pk.x = pk2bf(acc[0] * inv, acc[1] * inv);
    pk.y = pk2bf(acc[2] * inv, acc[3] * inv);
    *(uint2*)&attb[(size_t)q * DIM + h * HEAD_DIM + dq] = pk;
}

// ---------------------------------------------------------------------------
extern "C" void kernel_launch(void* const* d_in, const int* in_sizes, int n_in,
                              void* d_out, int out_size, void* d_ws, size_t ws_size,
                              hipStream_t stream)
{
    const float* hs    = (const float*)d_in[0];
    const float* cosf  = (const float*)d_in[1];
    const float* sinf  = (const float*)d_in[2];
    const float* w_qkv = (const float*)d_in[3];
    const float* b_qkv = (const float*)d_in[4];
    const float* g_q   = (const float*)d_in[5];
    const float* g_k   = (const float*)d_in[6];
    const float* w_out = (const float*)d_in[7];
    const float* b_out = (const float*)d_in[8];

    // workspace layout (same offsets; part_o = 240 slots x 256 x 128 bf16).
    char* base = (char*)d_ws;
    unsigned short* qb     = (unsigned short*)base;                //  9,584,640
    unsigned short* kb     = (unsigned short*)(base + 9584640);    //  9,584,640
    unsigned short* vt     = (unsigned short*)(base + 19169280);   //  9,584,640 (alias hsb)
    unsigned short* hsb    = vt;
    unsigned short* qkvb   = (unsigned short*)(base + 28753920);   // 28,753,920
    unsigned short* part_o = (unsigned short*)(base + 28753920);   // 15,728,640 (alias qkvb)
    float*          part_ml= (float*)(base + 60211200);            //    245,760 (alias qkvb)
    unsigned short* wqkvT  = (unsigned short*)(base + 81469440);   // 14,155,776 (alias attb)
    unsigned short* attb   = wqkvT;
    unsigned short* woutT  = (unsigned short*)(base + 95625216);   //  4,718,592
    float* outp = (float*)d_out;

    // 1) fused prep: hs->bf16 + both weight transposes (one launch)
    prep_kernel<<<4644, 256, 0, stream>>>(hs, hsb, w_qkv, wqkvT, w_out, woutT);
    // 2) qkvb = hs @ w_qkv + b_qkv (bf16 out), 256^2 pipelined tile
    gemm256_bf16_kernel<<<234, 512, 0, stream>>>(
        hsb, wqkvT, b_qkv, qkvb, SEQ_LEN, QKV_N, DIM);
    // 3) fused rmsnorm+rope (-> qb,kb) and v-transpose (-> vt), one launch
    rope_vt_kernel<<<SEQ_LEN + 49 * HEADS, 256, 0, stream>>>(
        qkvb, g_q, g_k, cosf, sinf, qb, kb, vt);
    // 4) attention pass 1: 240 blocks x 512 threads; frame-1 tiles -> attb direct
    attn_part_kernel<<<240, 512, 0, stream>>>(qb, kb, vt, part_o, part_ml, attb);
    // 5) combine (q >= 1536 only) -> attb bf16 [s][h*128+d]
    attn_combine_kernel<<<dim3((SEQ_LEN - 1536) / 8, HEADS), 256, 0, stream>>>(
        part_o, part_ml, attb);
    // 6) out = attb @ w_out + b_out (fp32), 128^2 BK=64 pipelined tile (300 blocks)
    gemm128_f32_kernel<<<304, 256, 0, stream>>>(
        attb, woutT, b_out, outp, SEQ_LEN, DIM, DIM);
}